// Round 4
// baseline (266.500 us; speedup 1.0000x reference)
//
#include <hip/hip_runtime.h>
#include <stdint.h>

typedef float f32x4 __attribute__((ext_vector_type(4)));
typedef __bf16 bf16x8 __attribute__((ext_vector_type(8)));
typedef unsigned short ushortx8 __attribute__((ext_vector_type(8)));

#define D_DIM 512
#define KGC 10
#define NCLU 8
#define BATCH 32
#define WPOS 250
#define WPAD 256
#define KDIM 3584   // 512*7
#define MROWS 522   // 512 feat + 10 assign
#define MPAD 528    // Y rows allocated per batch
#define WROWS 640   // Wcat rows allocated

__device__ __forceinline__ float bf2f(unsigned short u) {
  union { unsigned int i; float f; } v; v.i = ((unsigned int)u) << 16; return v.f;
}
__device__ __forceinline__ unsigned short f2bf(float f) {
  union { float f; unsigned int i; } v; v.f = f;
  unsigned int r = v.i + 0x7FFFu + ((v.i >> 16) & 1u);
  return (unsigned short)(r >> 16);
}

__device__ __forceinline__ void load_lds16(const void* g, void* l) {
  __builtin_amdgcn_global_load_lds(
      (const __attribute__((address_space(1))) void*)g,
      (__attribute__((address_space(3))) void*)l, 16, 0, 0);
}

// ---------------- prep: Wcat(bf16) = [feat_w ; assign_w ; zeros], bcat fp32 ----------------
__global__ void prep_kernel(const float* __restrict__ fw,
                            const float* __restrict__ fb,
                            const float* __restrict__ aw,
                            const float* __restrict__ ab,
                            unsigned short* __restrict__ Wcat,
                            float* __restrict__ bcat) {
  int r = blockIdx.x;
  unsigned short* dst = Wcat + (size_t)r * KDIM;
  const float* src = (r < D_DIM) ? (fw + (size_t)r * KDIM)
                   : (r < MROWS) ? (aw + (size_t)(r - D_DIM) * KDIM)
                                 : nullptr;
  for (int i = threadIdx.x; i < KDIM / 4; i += 256) {
    unsigned short o0 = 0, o1 = 0, o2 = 0, o3 = 0;
    if (src) {
      float4 v = ((const float4*)src)[i];
      o0 = f2bf(v.x); o1 = f2bf(v.y); o2 = f2bf(v.z); o3 = f2bf(v.w);
    }
    ushort4 o; o.x = o0; o.y = o1; o.z = o2; o.w = o3;
    ((ushort4*)dst)[i] = o;
  }
  if (threadIdx.x == 0)
    bcat[r] = r < D_DIM ? fb[r] : (r < MROWS ? ab[r - D_DIM] : 0.f);
}

// ---------------- transpose: x[b][k][n] (fp32) -> Xt[row=b*256+n][k] (bf16) ----------------
__global__ __launch_bounds__(256) void transpose_kernel(
    const float* __restrict__ x, unsigned short* __restrict__ Xt) {
  __shared__ unsigned short tile[64][66];
  const int kt = blockIdx.x * 64, nt = blockIdx.y * 64, b = blockIdx.z;
  const float* xb = x + (size_t)b * (KDIM * WPOS);
  const int t = threadIdx.x;
  // phase 1: 64 k-rows x 16 groups of 4n; paired float2 loads (8B-aligned safe)
#pragma unroll
  for (int it = 0; it < 4; it++) {
    int id = it * 256 + t;
    int k = id >> 4, p = id & 15;
    int n = nt + p * 4;
    const float* row = xb + (size_t)(kt + k) * WPOS;
    float v0 = 0.f, v1 = 0.f, v2 = 0.f, v3 = 0.f;
    if (n < WPOS) {            // n even -> pair (n, n+1) fully in-bounds
      float2 a = *(const float2*)&row[n];
      v0 = a.x; v1 = a.y;
    }
    if (n + 3 < WPOS) {
      float2 bq = *(const float2*)&row[n + 2];
      v2 = bq.x; v3 = bq.y;
    }
    ushort4 o; o.x = f2bf(v0); o.y = f2bf(v1); o.z = f2bf(v2); o.w = f2bf(v3);
    *(ushort4*)&tile[k][p * 4] = o;
  }
  __syncthreads();
  // phase 2: 64 n-rows x 8 k-chunks of 8; b128 global stores
  unsigned short* xtb = Xt + (size_t)(b * WPAD + nt) * KDIM;
#pragma unroll
  for (int it = 0; it < 2; it++) {
    int id = it * 256 + t;
    int n = id >> 3, q = id & 7;
    ushortx8 o;
#pragma unroll
    for (int r = 0; r < 8; r++) o[r] = tile[8 * q + r][n];
    *(ushortx8*)&xtb[(size_t)n * KDIM + kt + 8 * q] = o;
  }
}

// ---------------- gemm_feat: Y[b][m][n] = relu( W[m][:] . Xt[n_glob][:] + b[m] ), m<512 ----------------
#define BM 128
#define BN 64
#define BK 64

__global__ __launch_bounds__(256) void gemm_feat(
    const unsigned short* __restrict__ Xt, const unsigned short* __restrict__ Wcat,
    const float* __restrict__ bcat, unsigned short* __restrict__ Y) {
  __shared__ __align__(16) unsigned short Wl[BM * BK];
  __shared__ __align__(16) unsigned short Xl[BN * BK];
  const int tid = threadIdx.x;
  const int mt = blockIdx.x, ntg = blockIdx.y;
  const int lane = tid & 63, wv = tid >> 6;
  const unsigned short* Wg = Wcat + (size_t)mt * BM * KDIM;
  const unsigned short* Xg = Xt + (size_t)ntg * BN * KDIM;

  const f32x4 zero = {0.f, 0.f, 0.f, 0.f};
  f32x4 acc[2][4];
#pragma unroll
  for (int i = 0; i < 2; i++)
#pragma unroll
    for (int j = 0; j < 4; j++) acc[i][j] = zero;

  const int wm = wv * 32;
  const int fr = lane & 15, kg = lane >> 4;
  const int sx = fr & 7;

  for (int kb = 0; kb < KDIM; kb += BK) {
    __syncthreads();
#pragma unroll
    for (int i = 0; i < 4; i++) {
      int s = i * 256 + tid;
      int row = s >> 3, p = s & 7;
      int blk = p ^ (row & 7);
      load_lds16(Wg + (size_t)row * KDIM + kb + blk * 8, &Wl[s * 8]);
    }
#pragma unroll
    for (int i = 0; i < 2; i++) {
      int s = i * 256 + tid;
      int row = s >> 3, p = s & 7;
      int blk = p ^ (row & 7);
      load_lds16(Xg + (size_t)row * KDIM + kb + blk * 8, &Xl[s * 8]);
    }
    __syncthreads();
#pragma unroll
    for (int ks = 0; ks < BK; ks += 32) {
      const int kb8 = (ks >> 3) + kg;
      bf16x8 af[2], bfr[4];
#pragma unroll
      for (int i = 0; i < 2; i++)
        af[i] = *(const bf16x8*)&Wl[(wm + i * 16 + fr) * BK + (kb8 ^ sx) * 8];
#pragma unroll
      for (int j = 0; j < 4; j++)
        bfr[j] = *(const bf16x8*)&Xl[(j * 16 + fr) * BK + (kb8 ^ sx) * 8];
#pragma unroll
      for (int i = 0; i < 2; i++)
#pragma unroll
        for (int j = 0; j < 4; j++)
          acc[i][j] = __builtin_amdgcn_mfma_f32_16x16x32_bf16(af[i], bfr[j], acc[i][j], 0, 0, 0);
    }
  }

  // C/D: col = lane&15 (n), row = (lane>>4)*4 + reg (m)
  const int b = ntg >> 2;
  const int nb = (ntg & 3) * BN;
  unsigned short* Yb = Y + (size_t)b * MPAD * WPAD;
  const int m0 = mt * BM + wm + kg * 4;
  const int n0 = nb + fr;
#pragma unroll
  for (int i = 0; i < 2; i++) {
#pragma unroll
    for (int r = 0; r < 4; r++) {
      int m = m0 + i * 16 + r;
      float bias = bcat[m];
#pragma unroll
      for (int j = 0; j < 4; j++) {
        float v = fmaxf(acc[i][j][r] + bias, 0.f);
        Yb[(size_t)m * WPAD + n0 + j * 16] = f2bf(v);
      }
    }
  }
}

// ---------------- gemm_assign: Y rows 512..527 = W[512..527][:] . Xt + bias (no relu) ----------------
// grid 256 blocks; block = 16m x 32n; 4 waves split K (896 each = 14 BK iters)
__global__ __launch_bounds__(256) void gemm_assign(
    const unsigned short* __restrict__ Xt, const unsigned short* __restrict__ Wcat,
    const float* __restrict__ bcat, unsigned short* __restrict__ Y) {
  __shared__ __align__(16) unsigned short Wl[4 * 16 * 64];  // [wave][16m][64k] swizzled
  __shared__ __align__(16) unsigned short Xl[4 * 32 * 64];  // [wave][32n][64k] swizzled
  __shared__ float Pl[4][16][32];
  const int tid = threadIdx.x;
  const int blk_n = blockIdx.x;
  const int n0 = blk_n * 32;
  const int lane = tid & 63, wv = tid >> 6;
  const int fr = lane & 15, kg = lane >> 4;
  const int sx = fr & 7;

  const f32x4 zero = {0.f, 0.f, 0.f, 0.f};
  f32x4 acc[2];
  acc[0] = zero; acc[1] = zero;

  for (int i = 0; i < 14; i++) {
    __syncthreads();
    // stage W: 512 slots = [wave][16 rows][8 blocks]
#pragma unroll
    for (int it = 0; it < 2; it++) {
      int s = it * 256 + tid;
      int wd = s >> 7, r = (s >> 3) & 15, p = s & 7;
      int blk = p ^ (r & 7);
      load_lds16(Wcat + (size_t)(D_DIM + r) * KDIM + wd * 896 + i * 64 + blk * 8,
                 &Wl[s * 8]);
    }
    // stage X: 1024 slots = [wave][32 rows][8 blocks]
#pragma unroll
    for (int it = 0; it < 4; it++) {
      int s = it * 256 + tid;
      int wd = s >> 8, r = (s >> 3) & 31, p = s & 7;
      int blk = p ^ (r & 7);
      load_lds16(Xt + (size_t)(n0 + r) * KDIM + wd * 896 + i * 64 + blk * 8,
                 &Xl[s * 8]);
    }
    __syncthreads();
#pragma unroll
    for (int ks = 0; ks < 64; ks += 32) {
      const int kb8 = (ks >> 3) + kg;
      bf16x8 af = *(const bf16x8*)&Wl[(wv * 16 + fr) * 64 + (kb8 ^ sx) * 8];
#pragma unroll
      for (int j = 0; j < 2; j++) {
        bf16x8 bfr = *(const bf16x8*)&Xl[(wv * 32 + j * 16 + fr) * 64 + (kb8 ^ sx) * 8];
        acc[j] = __builtin_amdgcn_mfma_f32_16x16x32_bf16(af, bfr, acc[j], 0, 0, 0);
      }
    }
  }

  // partials to LDS: C/D col=lane&15 (n within 16), row=(lane>>4)*4+reg (m)
  __syncthreads();
#pragma unroll
  for (int j = 0; j < 2; j++)
#pragma unroll
    for (int r = 0; r < 4; r++)
      Pl[wv][kg * 4 + r][j * 16 + fr] = acc[j][r];
  __syncthreads();

  // reduce over waves, add bias, store
#pragma unroll
  for (int it = 0; it < 2; it++) {
    int o = it * 256 + tid;
    int m = o >> 5, n = o & 31;
    float v = Pl[0][m][n] + Pl[1][m][n] + Pl[2][m][n] + Pl[3][m][n] + bcat[D_DIM + m];
    int ng = n0 + n;
    int b = ng >> 8, col = ng & 255;
    Y[(size_t)b * MPAD * WPAD + (size_t)(D_DIM + m) * WPAD + col] = f2bf(v);
  }
}

// ---------------- epilogue: softmax, agg, subtract centroids*s_sum, L2-normalize ----------------
__global__ __launch_bounds__(256) void epi_kernel(
    const unsigned short* __restrict__ Y, const float* __restrict__ cent,
    float* __restrict__ out) {
  __shared__ float soft[WPAD];
  __shared__ float red[4];
  const int b = blockIdx.x >> 3, k = blockIdx.x & 7;
  const int tid = threadIdx.x;
  const unsigned short* Yb = Y + (size_t)b * MPAD * WPAD;

  float sv = 0.f;
  if (tid < WPOS) {
    float lg[KGC];
    float mx = -1e30f;
#pragma unroll
    for (int j = 0; j < KGC; j++) {
      lg[j] = bf2f(Yb[(size_t)(D_DIM + j) * WPAD + tid]);
      mx = fmaxf(mx, lg[j]);
    }
    float s = 0.f, ek = 0.f;
#pragma unroll
    for (int j = 0; j < KGC; j++) {
      float e = __expf(lg[j] - mx);
      s += e;
      if (j == k) ek = e;
    }
    sv = ek / s;
  }
  soft[tid] = sv;
  __syncthreads();

  float v = sv;
#pragma unroll
  for (int o = 32; o > 0; o >>= 1) v += __shfl_down(v, o, 64);
  if ((tid & 63) == 0) red[tid >> 6] = v;
  __syncthreads();
  float ssum = red[0] + red[1] + red[2] + red[3];

  float a0 = 0.f, a1 = 0.f;
  const unsigned short* row0 = Yb + (size_t)tid * WPAD;
  const unsigned short* row1 = Yb + (size_t)(tid + 256) * WPAD;
  for (int w = 0; w < WPAD; w += 8) {
    ushortx8 f0 = *(const ushortx8*)(row0 + w);
    ushortx8 f1 = *(const ushortx8*)(row1 + w);
#pragma unroll
    for (int u = 0; u < 8; u++) {
      float s = soft[w + u];
      a0 += bf2f(f0[u]) * s;
      a1 += bf2f(f1[u]) * s;
    }
  }
  float c0 = a0 - cent[(size_t)tid * KGC + k] * ssum;
  float c1 = a1 - cent[(size_t)(tid + 256) * KGC + k] * ssum;

  __syncthreads();
  float q = c0 * c0 + c1 * c1;
#pragma unroll
  for (int o = 32; o > 0; o >>= 1) q += __shfl_down(q, o, 64);
  if ((tid & 63) == 0) red[tid >> 6] = q;
  __syncthreads();
  float norm = sqrtf(red[0] + red[1] + red[2] + red[3]);
  float inv = 1.f / fmaxf(norm, 1e-12f);

  float* ob = out + (size_t)b * (NCLU * D_DIM) + (size_t)k * D_DIM;
  ob[tid] = c0 * inv;
  ob[tid + 256] = c1 * inv;
}

extern "C" void kernel_launch(void* const* d_in, const int* in_sizes, int n_in,
                              void* d_out, int out_size, void* d_ws, size_t ws_size,
                              hipStream_t stream) {
  const float* x  = (const float*)d_in[0];
  const float* fw = (const float*)d_in[1];
  const float* fb = (const float*)d_in[2];
  const float* aw = (const float*)d_in[3];
  const float* ab = (const float*)d_in[4];
  const float* ce = (const float*)d_in[5];
  float* out = (float*)d_out;
  char* ws = (char*)d_ws;

  const size_t XT_BYTES = (size_t)BATCH * WPAD * KDIM * 2;  // 58,720,256
  const size_t WC_BYTES = (size_t)WROWS * KDIM * 2;         //  4,587,520
  const size_t BC_BYTES = (size_t)WROWS * 4;
  unsigned short* Xt = (unsigned short*)(ws);
  unsigned short* Wc = (unsigned short*)(ws + XT_BYTES);
  float*          bc = (float*)(ws + XT_BYTES + WC_BYTES);
  unsigned short* Yv = (unsigned short*)(ws + XT_BYTES + WC_BYTES + BC_BYTES);

  prep_kernel<<<MPAD, 256, 0, stream>>>(fw, fb, aw, ab, Wc, bc);
  transpose_kernel<<<dim3(KDIM / 64, WPAD / 64, BATCH), 256, 0, stream>>>(x, Xt);
  gemm_feat<<<dim3(4, 128), 256, 0, stream>>>(Xt, Wc, bc, Yv);
  gemm_assign<<<256, 256, 0, stream>>>(Xt, Wc, bc, Yv);
  epi_kernel<<<BATCH * NCLU, 256, 0, stream>>>(Yv, ce, out);
}

// Round 5
// 255.609 us; speedup vs baseline: 1.0426x; 1.0426x over previous
//
#include <hip/hip_runtime.h>
#include <stdint.h>

typedef float f32x4 __attribute__((ext_vector_type(4)));
typedef __bf16 bf16x8 __attribute__((ext_vector_type(8)));
typedef unsigned short ushortx8 __attribute__((ext_vector_type(8)));

#define D_DIM 512
#define KGC 10
#define NCLU 8
#define BATCH 32
#define WPOS 250
#define WPAD 256
#define KDIM 3584   // 512*7
#define MROWS 522   // 512 feat + 10 assign
#define MPAD 528    // Y rows per batch
#define MBIG 544    // rows computed by fused gemm (544 = 34*16)
#define KSPLIT 4
#define KCHUNK 896  // KDIM / KSPLIT
#define NSTEPS 14   // KCHUNK / 64
#define NTILES 128  // 32 batches * 4 n-tiles of 64

__device__ __forceinline__ float bf2f(unsigned short u) {
  union { unsigned int i; float f; } v; v.i = ((unsigned int)u) << 16; return v.f;
}
__device__ __forceinline__ unsigned short f2bf(float f) {
  union { float f; unsigned int i; } v; v.f = f;
  unsigned int r = v.i + 0x7FFFu + ((v.i >> 16) & 1u);
  return (unsigned short)(r >> 16);
}

__device__ __forceinline__ void load_lds16(const void* g, void* l) {
  __builtin_amdgcn_global_load_lds(
      (const __attribute__((address_space(1))) void*)g,
      (__attribute__((address_space(3))) void*)l, 16, 0, 0);
}

// ---------------- prep: Wcat(bf16) rows 0..543 = [feat_w ; assign_w ; zeros], bcat fp32 ----------------
__global__ void prep_kernel(const float* __restrict__ fw,
                            const float* __restrict__ fb,
                            const float* __restrict__ aw,
                            const float* __restrict__ ab,
                            unsigned short* __restrict__ Wcat,
                            float* __restrict__ bcat) {
  int r = blockIdx.x;
  unsigned short* dst = Wcat + (size_t)r * KDIM;
  const float* src = (r < D_DIM) ? (fw + (size_t)r * KDIM)
                   : (r < MROWS) ? (aw + (size_t)(r - D_DIM) * KDIM)
                                 : nullptr;
  for (int i = threadIdx.x; i < KDIM / 4; i += 256) {
    unsigned short o0 = 0, o1 = 0, o2 = 0, o3 = 0;
    if (src) {
      float4 v = ((const float4*)src)[i];
      o0 = f2bf(v.x); o1 = f2bf(v.y); o2 = f2bf(v.z); o3 = f2bf(v.w);
    }
    ushort4 o; o.x = o0; o.y = o1; o.z = o2; o.w = o3;
    ((ushort4*)dst)[i] = o;
  }
  if (threadIdx.x == 0)
    bcat[r] = r < D_DIM ? fb[r] : (r < MROWS ? ab[r - D_DIM] : 0.f);
}

// ---------------- fused GEMM: reads x directly (fp32), computes partial C[544m x 64n] over a K-chunk ----
// grid (128 n-tiles, 4 k-splits) = 512 blocks = 2/CU. Per step: W staged via swizzled global_load_lds,
// X staged via coalesced per-lane dword loads (lane = n) -> bf16 pack -> ds_write_b128 (transpose-free).
__global__ __launch_bounds__(256, 2) void gemm_fused(
    const float* __restrict__ x, const unsigned short* __restrict__ Wcat,
    float* __restrict__ P) {
  __shared__ __align__(16) unsigned short Wl[MBIG * 64];  // 69632 B, swizzled 16B k-blocks
  __shared__ __align__(16) unsigned short Xl[64 * 64];    //  8192 B, swizzled 16B k-blocks
  const int tid = threadIdx.x;
  const int nt = blockIdx.x, sp = blockIdx.y;
  const int b = nt >> 2, n0 = (nt & 3) * 64;
  const int lane = tid & 63, wv = tid >> 6;
  const int fr = lane & 15, kg = lane >> 4;
  const int sx = fr & 7;
  const int nloc = tid & 63;          // n this thread stages
  const int nglob = n0 + nloc;
  const bool okn = nglob < WPOS;
  const int kb0 = tid >> 6;           // k-block pair base (kb0, kb0+4)
  const float* xb = x + (size_t)b * KDIM * WPOS + nglob;
  const int kbase = sp * KCHUNK;

  float vx[16];
  // prologue: x values for step 0
#pragma unroll
  for (int pass = 0; pass < 2; pass++) {
    int kb = kb0 + 4 * pass;
#pragma unroll
    for (int e = 0; e < 8; e++) {
      int k = kbase + kb * 8 + e;
      vx[pass * 8 + e] = okn ? xb[(size_t)k * WPOS] : 0.f;
    }
  }

  const f32x4 zero = {0.f, 0.f, 0.f, 0.f};
  f32x4 acc[8][4];
#pragma unroll
  for (int i = 0; i < 8; i++)
#pragma unroll
    for (int j = 0; j < 4; j++) acc[i][j] = zero;
  f32x4 acca = zero;

  for (int st = 0; st < NSTEPS; st++) {
    const int kst = kbase + st * 64;
    __syncthreads();
    // commit staged x (step st) to Xl
#pragma unroll
    for (int pass = 0; pass < 2; pass++) {
      int kb = kb0 + 4 * pass;
      ushortx8 pk;
#pragma unroll
      for (int e = 0; e < 8; e++) pk[e] = f2bf(vx[pass * 8 + e]);
      *(ushortx8*)&Xl[nloc * 64 + (kb ^ (nloc & 7)) * 8] = pk;
    }
    // stage W tile (544 rows x 64 k), swizzled
#pragma unroll
    for (int it = 0; it < 17; it++) {
      int s = it * 256 + tid;
      int row = s >> 3, p = s & 7;
      int blk = p ^ (row & 7);
      load_lds16(Wcat + (size_t)row * KDIM + kst + blk * 8, &Wl[s * 8]);
    }
    __syncthreads();
    // prefetch x for step st+1 (latency hidden under the MFMA loop)
    if (st + 1 < NSTEPS) {
      const int kst2 = kst + 64;
#pragma unroll
      for (int pass = 0; pass < 2; pass++) {
        int kb = kb0 + 4 * pass;
#pragma unroll
        for (int e = 0; e < 8; e++) {
          int k = kst2 + kb * 8 + e;
          vx[pass * 8 + e] = okn ? xb[(size_t)k * WPOS] : 0.f;
        }
      }
    }
    // MFMA: 66 per wave per step
#pragma unroll
    for (int ks = 0; ks < 64; ks += 32) {
      const int off = (((ks >> 3) + kg) ^ sx) * 8;
      bf16x8 bfr[4];
#pragma unroll
      for (int j = 0; j < 4; j++)
        bfr[j] = *(const bf16x8*)&Xl[(j * 16 + fr) * 64 + off];
      // assign rows (512..527), this wave's n-quarter
      {
        bf16x8 aas = *(const bf16x8*)&Wl[(512 + fr) * 64 + off];
        bf16x8 bfa = *(const bf16x8*)&Xl[(wv * 16 + fr) * 64 + off];
        acca = __builtin_amdgcn_mfma_f32_16x16x32_bf16(aas, bfa, acca, 0, 0, 0);
      }
#pragma unroll
      for (int i = 0; i < 8; i++) {
        bf16x8 af = *(const bf16x8*)&Wl[(wv * 128 + i * 16 + fr) * 64 + off];
#pragma unroll
        for (int j = 0; j < 4; j++)
          acc[i][j] = __builtin_amdgcn_mfma_f32_16x16x32_bf16(af, bfr[j], acc[i][j], 0, 0, 0);
      }
    }
  }

  // store partials. C/D: col = lane&15 (n), row = kg*4 + r (m within 16)
  float* Pb = P + (size_t)(sp * NTILES + nt) * (MBIG * 64);
#pragma unroll
  for (int i = 0; i < 8; i++) {
#pragma unroll
    for (int r = 0; r < 4; r++) {
      int m = wv * 128 + i * 16 + kg * 4 + r;
#pragma unroll
      for (int j = 0; j < 4; j++)
        Pb[(size_t)m * 64 + j * 16 + fr] = acc[i][j][r];
    }
  }
#pragma unroll
  for (int r = 0; r < 4; r++)
    Pb[(size_t)(512 + kg * 4 + r) * 64 + wv * 16 + fr] = acca[r];
}

// ---------------- reduce: Y[b][m][n](bf16) = relu_if_feat( sum_sp P + bias ) ----------------
__global__ __launch_bounds__(256) void reduce_kernel(
    const float* __restrict__ P, const float* __restrict__ bcat,
    unsigned short* __restrict__ Y) {
  const int nt = blockIdx.x, mg = blockIdx.y;
  const int t = threadIdx.x;
  const int m = mg * 32 + (t >> 3);
  const int nl = (t & 7) * 8;
  if (m >= MPAD) return;
  const size_t base = (size_t)nt * (MBIG * 64) + (size_t)m * 64 + nl;
  const size_t spstr = (size_t)NTILES * (MBIG * 64);
  float s[8];
#pragma unroll
  for (int e = 0; e < 8; e++) s[e] = 0.f;
#pragma unroll
  for (int sp = 0; sp < KSPLIT; sp++) {
    const float* p = P + sp * spstr + base;
    float4 a = *(const float4*)p;
    float4 c = *(const float4*)(p + 4);
    s[0] += a.x; s[1] += a.y; s[2] += a.z; s[3] += a.w;
    s[4] += c.x; s[5] += c.y; s[6] += c.z; s[7] += c.w;
  }
  float bias = bcat[m];
  ushortx8 o;
#pragma unroll
  for (int e = 0; e < 8; e++) {
    float v = s[e] + bias;
    if (m < D_DIM) v = fmaxf(v, 0.f);
    o[e] = f2bf(v);
  }
  const int bb = nt >> 2, c0 = (nt & 3) * 64 + nl;
  *(ushortx8*)&Y[(size_t)bb * MPAD * WPAD + (size_t)m * WPAD + c0] = o;
}

// ---------------- epilogue: softmax, agg, subtract centroids*s_sum, L2-normalize ----------------
__global__ __launch_bounds__(256) void epi_kernel(
    const unsigned short* __restrict__ Y, const float* __restrict__ cent,
    float* __restrict__ out) {
  __shared__ float soft[WPAD];
  __shared__ float red[4];
  const int b = blockIdx.x >> 3, k = blockIdx.x & 7;
  const int tid = threadIdx.x;
  const unsigned short* Yb = Y + (size_t)b * MPAD * WPAD;

  float sv = 0.f;
  if (tid < WPOS) {
    float lg[KGC];
    float mx = -1e30f;
#pragma unroll
    for (int j = 0; j < KGC; j++) {
      lg[j] = bf2f(Yb[(size_t)(D_DIM + j) * WPAD + tid]);
      mx = fmaxf(mx, lg[j]);
    }
    float s = 0.f, ek = 0.f;
#pragma unroll
    for (int j = 0; j < KGC; j++) {
      float e = __expf(lg[j] - mx);
      s += e;
      if (j == k) ek = e;
    }
    sv = ek / s;
  }
  soft[tid] = sv;
  __syncthreads();

  float v = sv;
#pragma unroll
  for (int o = 32; o > 0; o >>= 1) v += __shfl_down(v, o, 64);
  if ((tid & 63) == 0) red[tid >> 6] = v;
  __syncthreads();
  float ssum = red[0] + red[1] + red[2] + red[3];

  float a0 = 0.f, a1 = 0.f;
  const unsigned short* row0 = Yb + (size_t)tid * WPAD;
  const unsigned short* row1 = Yb + (size_t)(tid + 256) * WPAD;
  for (int w = 0; w < WPAD; w += 8) {
    ushortx8 f0 = *(const ushortx8*)(row0 + w);
    ushortx8 f1 = *(const ushortx8*)(row1 + w);
#pragma unroll
    for (int u = 0; u < 8; u++) {
      float s = soft[w + u];
      a0 += bf2f(f0[u]) * s;
      a1 += bf2f(f1[u]) * s;
    }
  }
  float c0 = a0 - cent[(size_t)tid * KGC + k] * ssum;
  float c1 = a1 - cent[(size_t)(tid + 256) * KGC + k] * ssum;

  __syncthreads();
  float q = c0 * c0 + c1 * c1;
#pragma unroll
  for (int o = 32; o > 0; o >>= 1) q += __shfl_down(q, o, 64);
  if ((tid & 63) == 0) red[tid >> 6] = q;
  __syncthreads();
  float norm = sqrtf(red[0] + red[1] + red[2] + red[3]);
  float inv = 1.f / fmaxf(norm, 1e-12f);

  float* ob = out + (size_t)b * (NCLU * D_DIM) + (size_t)k * D_DIM;
  ob[tid] = c0 * inv;
  ob[tid + 256] = c1 * inv;
}

extern "C" void kernel_launch(void* const* d_in, const int* in_sizes, int n_in,
                              void* d_out, int out_size, void* d_ws, size_t ws_size,
                              hipStream_t stream) {
  const float* x  = (const float*)d_in[0];
  const float* fw = (const float*)d_in[1];
  const float* fb = (const float*)d_in[2];
  const float* aw = (const float*)d_in[3];
  const float* ab = (const float*)d_in[4];
  const float* ce = (const float*)d_in[5];
  float* out = (float*)d_out;
  char* ws = (char*)d_ws;

  const size_t WC_BYTES = (size_t)640 * KDIM * 2;               // 4,587,520
  const size_t BC_BYTES = 4096;                                 // 544 floats, padded
  const size_t P_BYTES  = (size_t)KSPLIT * NTILES * MBIG * 64 * 4;  // 71,303,168
  unsigned short* Wc = (unsigned short*)(ws);
  float*          bc = (float*)(ws + WC_BYTES);
  float*          P  = (float*)(ws + WC_BYTES + BC_BYTES);
  unsigned short* Yv = (unsigned short*)(ws + WC_BYTES + BC_BYTES + P_BYTES);
  // total ws use ~84.5 MB

  prep_kernel<<<MBIG, 256, 0, stream>>>(fw, fb, aw, ab, Wc, bc);
  gemm_fused<<<dim3(NTILES, KSPLIT), 256, 0, stream>>>(x, Wc, P);
  reduce_kernel<<<dim3(NTILES, 17), 256, 0, stream>>>(P, bc, Yv);
  epi_kernel<<<BATCH * NCLU, 256, 0, stream>>>(Yv, ce, out);
}